// Round 1
// baseline (853.684 us; speedup 1.0000x reference)
//
#include <hip/hip_runtime.h>
#include <cstddef>

// DynamicNetwork: B=8192, ND=13, NS=26, D=16, BIN=BOUT=400, NB=4, K=4
// CH1=[0,1,1,1], CH2=[1,2,3,4], CHK=[0,1,2,3]
// chain: node2 = blk0(node0,node1); node3 = blk1(node1,node2);
//        node4 = blk2(node1,node3); node5 = blk3(node1,node4)
// x@P = s*(N@P) + c*colsum(P)  (alpha scalars folded into GEMM epilogue)

__global__ __launch_bounds__(256) void prep_kernel(
    const float* __restrict__ Pd, const float* __restrict__ Ps, const float* __restrict__ Pb,
    const float* __restrict__ a0, const float* __restrict__ a1,
    const float* __restrict__ a2, const float* __restrict__ a3,
    float* __restrict__ scal, float* __restrict__ sumsq,
    float* __restrict__ csd, float* __restrict__ css, float* __restrict__ csb)
{
    int gid = blockIdx.x * 256 + threadIdx.x;
    if (gid < 400) {
        float s = 0.f;
        for (int k = 0; k < 208; ++k) s += Pd[k*400 + gid];
        csd[gid] = s;
    } else if (gid < 800) {
        int j = gid - 400; float s = 0.f;
        for (int k = 0; k < 416; ++k) s += Ps[k*400 + j];
        css[j] = s;
    } else if (gid < 1200) {
        int j = gid - 800; float s = 0.f;
        for (int k = 0; k < 400; ++k) s += Pb[k*400 + j];
        csb[j] = s;
    } else if (gid < 1204) {
        int i = gid - 1200;
        const float* a = (i==0) ? a0 : (i==1) ? a1 : (i==2) ? a2 : a3;
        int np = 2 + i;
        float sum1 = 0.f, sum2 = 0.f, sumc = 0.f;
        for (int j = 0; j < np; ++j) { sum1 += a[j]; sum2 += a[np+j]; }
        for (int j = 0; j < 4; ++j) sumc += a[2*np+j];
        int i1 = (i==0) ? 0 : 1;
        int i2 = i + 1;
        int kk = i;
        float s1 = a[i1],      c1 = sum1 - s1;   // x1 term
        float s2 = a[np+i2],   c2 = sum2 - s2;   // x2 term
        float sk = a[2*np+kk], ck = sumc - sk;   // out combine
        float* sl = scal + i*8;
        // epilogue order: [sa,ca] = scalars for the GEMM's A-operand term,
        //                 [ss,cs] = scalars for the precomputed-S (node1@Ps) term
        if (i == 0) { sl[0]=s1; sl[1]=c1; sl[2]=s2; sl[3]=c2; }  // A=node0@Pd, S-term=x2
        else        { sl[0]=s2; sl[1]=c2; sl[2]=s1; sl[3]=c1; }  // A=node_{i2}@Pb, S-term=x1
        sl[4] = sk; sl[5] = ck;
    } else if (gid < 1206) {
        sumsq[gid - 1204] = 0.f;
    }
}

__global__ __launch_bounds__(256) void embed_kernel(
    const float* __restrict__ rd, const int* __restrict__ rs,
    const float* __restrict__ emb,
    float* __restrict__ node0, float* __restrict__ node1,
    float* __restrict__ sumsq)
{
    int b = blockIdx.x;
    int t = threadIdx.x;
    float dsq = 0.f, ssq = 0.f;
    if (t < 208) {
        int f = t >> 4, d = t & 15;
        float v = emb[f*16 + d] * rd[b*13 + f];
        node0[(size_t)b*208 + t] = v;
        dsq = v*v;
    }
    for (int e = t; e < 416; e += 256) {
        int s = e >> 4, d = e & 15;
        int row = 13 + 50000*s + rs[b*26 + s];
        float v = emb[(size_t)row*16 + d];
        node1[(size_t)b*416 + e] = v;
        ssq += v*v;
    }
    float v1 = dsq, v2 = ssq;
    for (int o = 32; o > 0; o >>= 1) { v1 += __shfl_down(v1, o); v2 += __shfl_down(v2, o); }
    __shared__ float red[8];
    int wave = t >> 6, lane = t & 63;
    if (lane == 0) { red[wave] = v1; red[4+wave] = v2; }
    __syncthreads();
    if (t == 0) {
        atomicAdd(&sumsq[0], red[0]+red[1]+red[2]+red[3]);
        atomicAdd(&sumsq[1], red[4]+red[5]+red[6]+red[7]);
    }
}

__global__ __launch_bounds__(256) void init_out_kernel(
    const float* __restrict__ clf_b, const float* __restrict__ sumsq, float* __restrict__ out)
{
    int g = blockIdx.x * 256 + threadIdx.x;
    if (g < 8192) out[g] = clf_b[0];
    else if (g == 8192) out[8192] = 1e-5f * (sqrtf(sumsq[0]) + sqrtf(sumsq[1]));
}

// C[M=8192, N<=400] = A[M,Kd] @ W[Kd,400-sliced]; mode epilogues:
//  0: C = acc
//  1: C = relu(sa*acc + ca*csA[j] + ss*S[b,j] + cs*csS[j])
//  2: C = sk*(acc + bias[j]) + ck
__global__ __launch_bounds__(256) void gemm_kernel(
    const float* __restrict__ A, const float* __restrict__ W, float* __restrict__ C,
    int Kd, int N, int mode,
    const float* __restrict__ S, const float* __restrict__ csA, const float* __restrict__ csS,
    const float* __restrict__ sc, const float* __restrict__ bias)
{
    __shared__ float As[16][68];  // [k][m], pad 68 -> float4-aligned, 2-way-bank max
    __shared__ float Ws[16][68];  // [k][n]
    int tid = threadIdx.x;
    int tx = tid & 15, ty = tid >> 4;
    int bm = blockIdx.y * 64;
    int bn = blockIdx.x * 64;
    int arow = tid >> 2;
    int ak4  = (tid & 3) << 2;
    int wrow = tid >> 4;
    int wc4  = (tid & 15) << 2;
    int wcol = bn + wc4;
    bool wok = (wcol < N);
    const float* Ap = A + (size_t)(bm + arow)*Kd + ak4;
    const float* Wp = W + (size_t)wrow*400 + wcol;
    float acc[4][4] = {};
    for (int k0 = 0; k0 < Kd; k0 += 16) {
        float4 av = *(const float4*)(Ap + k0);
        float4 wv = make_float4(0.f,0.f,0.f,0.f);
        if (wok) wv = *(const float4*)(Wp + (size_t)k0*400);
        __syncthreads();
        As[ak4+0][arow] = av.x;
        As[ak4+1][arow] = av.y;
        As[ak4+2][arow] = av.z;
        As[ak4+3][arow] = av.w;
        *(float4*)&Ws[wrow][wc4] = wv;
        __syncthreads();
        #pragma unroll
        for (int kk = 0; kk < 16; ++kk) {
            float4 a4 = *(const float4*)&As[kk][ty<<2];
            float4 b4 = *(const float4*)&Ws[kk][tx<<2];
            acc[0][0] += a4.x*b4.x; acc[0][1] += a4.x*b4.y; acc[0][2] += a4.x*b4.z; acc[0][3] += a4.x*b4.w;
            acc[1][0] += a4.y*b4.x; acc[1][1] += a4.y*b4.y; acc[1][2] += a4.y*b4.z; acc[1][3] += a4.y*b4.w;
            acc[2][0] += a4.z*b4.x; acc[2][1] += a4.z*b4.y; acc[2][2] += a4.z*b4.z; acc[2][3] += a4.z*b4.w;
            acc[3][0] += a4.w*b4.x; acc[3][1] += a4.w*b4.y; acc[3][2] += a4.w*b4.z; acc[3][3] += a4.w*b4.w;
        }
    }
    int gn = bn + (tx << 2);
    if (gn >= N) return;
    int gm = bm + (ty << 2);
    if (mode == 0) {
        #pragma unroll
        for (int i = 0; i < 4; ++i) {
            float4 v = make_float4(acc[i][0], acc[i][1], acc[i][2], acc[i][3]);
            *(float4*)&C[(size_t)(gm+i)*400 + gn] = v;
        }
    } else if (mode == 1) {
        float sa = sc[0], ca = sc[1], ss = sc[2], cs = sc[3];
        float4 cA = *(const float4*)&csA[gn];
        float4 cS = *(const float4*)&csS[gn];
        #pragma unroll
        for (int i = 0; i < 4; ++i) {
            float4 sv = *(const float4*)&S[(size_t)(gm+i)*400 + gn];
            float4 v;
            v.x = fmaxf(sa*acc[i][0] + ca*cA.x + ss*sv.x + cs*cS.x, 0.f);
            v.y = fmaxf(sa*acc[i][1] + ca*cA.y + ss*sv.y + cs*cS.y, 0.f);
            v.z = fmaxf(sa*acc[i][2] + ca*cA.z + ss*sv.z + cs*cS.z, 0.f);
            v.w = fmaxf(sa*acc[i][3] + ca*cA.w + ss*sv.w + cs*cS.w, 0.f);
            *(float4*)&C[(size_t)(gm+i)*400 + gn] = v;
        }
    } else {
        float sk = sc[4], ck = sc[5];
        float4 bv = *(const float4*)&bias[gn];
        #pragma unroll
        for (int i = 0; i < 4; ++i) {
            float4 v;
            v.x = sk*(acc[i][0] + bv.x) + ck;
            v.y = sk*(acc[i][1] + bv.y) + ck;
            v.z = sk*(acc[i][2] + bv.z) + ck;
            v.w = sk*(acc[i][3] + bv.w) + ck;
            *(float4*)&C[(size_t)(gm+i)*400 + gn] = v;
        }
    }
}

__global__ __launch_bounds__(256) void acc_logits_kernel(
    const float* __restrict__ node, const float* __restrict__ w, float* __restrict__ out)
{
    int wave = threadIdx.x >> 6, lane = threadIdx.x & 63;
    int row = blockIdx.x*4 + wave;
    const float* nr = node + (size_t)row*400;
    float s = 0.f;
    for (int j = lane; j < 400; j += 64) s += nr[j]*w[j];
    for (int o = 32; o > 0; o >>= 1) s += __shfl_down(s, o);
    if (lane == 0) out[row] += s;
}

extern "C" void kernel_launch(void* const* d_in, const int* in_sizes, int n_in,
                              void* d_out, int out_size, void* d_ws, size_t ws_size,
                              hipStream_t stream)
{
    const float* raw_dense  = (const float*)d_in[0];
    const int*   raw_sparse = (const int*)d_in[1];
    const float* emb   = (const float*)d_in[2];
    const float* Pd    = (const float*)d_in[3];
    const float* Ps    = (const float*)d_in[4];
    const float* Pb    = (const float*)d_in[5];
    const float* Wc    = (const float*)d_in[6];
    const float* bc    = (const float*)d_in[7];
    const float* clf_w = (const float*)d_in[8];
    const float* clf_b = (const float*)d_in[9];
    const float* a0 = (const float*)d_in[10];
    const float* a1 = (const float*)d_in[11];
    const float* a2 = (const float*)d_in[12];
    const float* a3 = (const float*)d_in[13];
    float* out = (float*)d_out;
    float* ws  = (float*)d_ws;

    float* scal  = ws;
    float* sumsq = ws + 32;
    float* csd   = ws + 64;
    float* css   = ws + 464;
    float* csb   = ws + 864;
    float* node0 = ws + 1280;
    float* node1 = node0 + (size_t)8192*208;
    float* S1    = node1 + (size_t)8192*416;   // node1 @ P_sparse, reused by all 4 blocks
    float* hbuf  = S1    + (size_t)8192*400;
    float* nA    = hbuf  + (size_t)8192*400;
    float* nB    = nA    + (size_t)8192*400;

    prep_kernel<<<5,256,0,stream>>>(Pd,Ps,Pb,a0,a1,a2,a3,scal,sumsq,csd,css,csb);
    embed_kernel<<<8192,256,0,stream>>>(raw_dense, raw_sparse, emb, node0, node1, sumsq);
    init_out_kernel<<<33,256,0,stream>>>(clf_b, sumsq, out);

    dim3 gg(7,128);
    // shared term: S1 = node1 @ P_sparse
    gemm_kernel<<<gg,256,0,stream>>>(node1, Ps, S1, 416, 400, 0, nullptr,nullptr,nullptr,nullptr,nullptr);
    // block 0: h = relu(s*(node0@Pd)+c*csd + s'*S1+c'*css); node2 = sk*(h@Wc00+bc00)+ck
    gemm_kernel<<<gg,256,0,stream>>>(node0, Pd, hbuf, 208, 400, 1, S1, csd, css, scal+0, nullptr);
    gemm_kernel<<<gg,256,0,stream>>>(hbuf, Wc, nA, 400, 400, 2, nullptr,nullptr,nullptr, scal+0, bc);
    acc_logits_kernel<<<2048,256,0,stream>>>(nA, clf_w, out);
    // block 1: A = node2 @ Pb
    gemm_kernel<<<gg,256,0,stream>>>(nA, Pb, hbuf, 400, 400, 1, S1, csb, css, scal+8, nullptr);
    gemm_kernel<<<gg,256,0,stream>>>(hbuf, Wc + (size_t)5*160000, nB, 400, 400, 2, nullptr,nullptr,nullptr, scal+8, bc + 5*400);
    acc_logits_kernel<<<2048,256,0,stream>>>(nB, clf_w + 400, out);
    // block 2
    gemm_kernel<<<gg,256,0,stream>>>(nB, Pb, hbuf, 400, 400, 1, S1, csb, css, scal+16, nullptr);
    gemm_kernel<<<gg,256,0,stream>>>(hbuf, Wc + (size_t)10*160000, nA, 400, 400, 2, nullptr,nullptr,nullptr, scal+16, bc + 10*400);
    acc_logits_kernel<<<2048,256,0,stream>>>(nA, clf_w + 800, out);
    // block 3
    gemm_kernel<<<gg,256,0,stream>>>(nA, Pb, hbuf, 400, 400, 1, S1, csb, css, scal+24, nullptr);
    gemm_kernel<<<gg,256,0,stream>>>(hbuf, Wc + (size_t)15*160000, nB, 400, 400, 2, nullptr,nullptr,nullptr, scal+24, bc + 15*400);
    acc_logits_kernel<<<2048,256,0,stream>>>(nB, clf_w + 1200, out);
}

// Round 2
// 673.730 us; speedup vs baseline: 1.2671x; 1.2671x over previous
//
#include <hip/hip_runtime.h>
#include <cstddef>

// DynamicNetwork: B=8192, ND=13, NS=26, D=16, BIN=BOUT=400, NB=4, K=4
// chain: node2 = blk0(node0,node1); node3 = blk1(node1,node2);
//        node4 = blk2(node1,node3); node5 = blk3(node1,node4)
// x@P = s*(N@P) + c*colsum(P)  (alpha scalars folded into GEMM epilogue)

#define EMB_BLOCKS 1024

__global__ __launch_bounds__(256) void prep_kernel(
    const float* __restrict__ Pd, const float* __restrict__ Ps, const float* __restrict__ Pb,
    const float* __restrict__ a0, const float* __restrict__ a1,
    const float* __restrict__ a2, const float* __restrict__ a3,
    float* __restrict__ scal,
    float* __restrict__ csd, float* __restrict__ css, float* __restrict__ csb)
{
    int gid = blockIdx.x * 256 + threadIdx.x;
    if (gid < 400) {
        float s = 0.f;
        for (int k = 0; k < 208; ++k) s += Pd[k*400 + gid];
        csd[gid] = s;
    } else if (gid < 800) {
        int j = gid - 400; float s = 0.f;
        for (int k = 0; k < 416; ++k) s += Ps[k*400 + j];
        css[j] = s;
    } else if (gid < 1200) {
        int j = gid - 800; float s = 0.f;
        for (int k = 0; k < 400; ++k) s += Pb[k*400 + j];
        csb[j] = s;
    } else if (gid < 1204) {
        int i = gid - 1200;
        const float* a = (i==0) ? a0 : (i==1) ? a1 : (i==2) ? a2 : a3;
        int np = 2 + i;
        float sum1 = 0.f, sum2 = 0.f, sumc = 0.f;
        for (int j = 0; j < np; ++j) { sum1 += a[j]; sum2 += a[np+j]; }
        for (int j = 0; j < 4; ++j) sumc += a[2*np+j];
        int i1 = (i==0) ? 0 : 1;
        int i2 = i + 1;
        int kk = i;
        float s1 = a[i1],      c1 = sum1 - s1;   // x1 term
        float s2 = a[np+i2],   c2 = sum2 - s2;   // x2 term
        float sk = a[2*np+kk], ck = sumc - sk;   // out combine
        float* sl = scal + i*8;
        if (i == 0) { sl[0]=s1; sl[1]=c1; sl[2]=s2; sl[3]=c2; }  // A=node0@Pd, S-term=x2
        else        { sl[0]=s2; sl[1]=c2; sl[2]=s1; sl[3]=c1; }  // A=node_{i2}@Pb, S-term=x1
        sl[4] = sk; sl[5] = ck;
    }
}

__global__ __launch_bounds__(256) void embed_kernel(
    const float* __restrict__ rd, const int* __restrict__ rs,
    const float* __restrict__ emb,
    float* __restrict__ node0, float* __restrict__ node1,
    float* __restrict__ partial)
{
    int tid0 = blockIdx.x*256 + threadIdx.x;
    int nth = gridDim.x*256;
    float ssq = 0.f, dsq = 0.f;
    // sparse: 8192 * 26 slots * 4 float4 = 851968 items
    for (int it = tid0; it < 8192*26*4; it += nth) {
        int b = it / 104;
        int r = it - b*104;
        int slot = r >> 2, v = r & 3;
        int row = 13 + 50000*slot + rs[b*26 + slot];
        float4 e = *(const float4*)&emb[(size_t)row*16 + v*4];
        *(float4*)&node1[(size_t)b*416 + slot*16 + v*4] = e;
        ssq += e.x*e.x + e.y*e.y + e.z*e.z + e.w*e.w;
    }
    // dense: 8192 * 13 feats * 4 float4 = 425984 items
    for (int it = tid0; it < 8192*13*4; it += nth) {
        int b = it / 52;
        int r = it - b*52;
        int f = r >> 2, v = r & 3;
        float s = rd[b*13 + f];
        float4 e = *(const float4*)&emb[f*16 + v*4];
        e.x *= s; e.y *= s; e.z *= s; e.w *= s;
        *(float4*)&node0[(size_t)b*208 + f*16 + v*4] = e;
        dsq += e.x*e.x + e.y*e.y + e.z*e.z + e.w*e.w;
    }
    for (int o = 32; o > 0; o >>= 1) { ssq += __shfl_down(ssq, o); dsq += __shfl_down(dsq, o); }
    __shared__ float red[8];
    int wave = threadIdx.x >> 6, lane = threadIdx.x & 63;
    if (lane == 0) { red[wave] = dsq; red[4+wave] = ssq; }
    __syncthreads();
    if (threadIdx.x == 0) {
        partial[blockIdx.x*2]   = red[0]+red[1]+red[2]+red[3];
        partial[blockIdx.x*2+1] = red[4]+red[5]+red[6]+red[7];
    }
}

// blocks 0..31: out[g] = clf_b; block 32: reduce partials -> out[8192]
__global__ __launch_bounds__(256) void finalize_kernel(
    const float* __restrict__ clf_b, const float* __restrict__ partial, float* __restrict__ out)
{
    if (blockIdx.x < 32) {
        out[blockIdx.x*256 + threadIdx.x] = clf_b[0];
        return;
    }
    float d = 0.f, s = 0.f;
    for (int i = threadIdx.x; i < EMB_BLOCKS; i += 256) { d += partial[2*i]; s += partial[2*i+1]; }
    for (int o = 32; o > 0; o >>= 1) { d += __shfl_down(d, o); s += __shfl_down(s, o); }
    __shared__ float red[8];
    int wave = threadIdx.x >> 6, lane = threadIdx.x & 63;
    if (lane == 0) { red[wave] = d; red[4+wave] = s; }
    __syncthreads();
    if (threadIdx.x == 0) {
        float dd = red[0]+red[1]+red[2]+red[3];
        float ss = red[4]+red[5]+red[6]+red[7];
        out[8192] = 1e-5f * (sqrtf(dd) + sqrtf(ss));
    }
}

// C[M=8192, N<=400] = A[M,Kd] @ W[Kd,400-sliced]; 128x64 tile, 8x4 microtile.
//  mode 0: C = acc
//  mode 1: C = relu(sa*acc + ca*csA[j] + ss*S[b,j] + cs*csS[j])
//  mode 2: C = sk*(acc + bias[j]) + ck
__global__ __launch_bounds__(256) void gemm_kernel(
    const float* __restrict__ A, const float* __restrict__ W, float* __restrict__ C,
    int Kd, int N, int mode,
    const float* __restrict__ S, const float* __restrict__ csA, const float* __restrict__ csS,
    const float* __restrict__ sc, const float* __restrict__ bias)
{
    __shared__ float As[16][132];  // [k][m], 128+4 pad
    __shared__ float Ws[16][68];   // [k][n]
    int tid = threadIdx.x;
    int tx = tid & 15;             // n quad
    int ty = tid >> 4;             // 0..15, 8 rows each
    int bm = blockIdx.y * 128;
    int bn = blockIdx.x * 64;
    int arow = tid >> 1;           // 0..127
    int ak8  = (tid & 1) << 3;     // 0 or 8
    int wrow = tid >> 4;
    int wc4  = (tid & 15) << 2;
    int wcol = bn + wc4;
    bool wok = (wcol < N);
    const float* Ap = A + (size_t)(bm + arow)*Kd + ak8;
    const float* Wp = W + (size_t)wrow*400 + wcol;
    float acc[8][4] = {};
    for (int k0 = 0; k0 < Kd; k0 += 16) {
        float4 av0 = *(const float4*)(Ap + k0);
        float4 av1 = *(const float4*)(Ap + k0 + 4);
        float4 wv = make_float4(0.f,0.f,0.f,0.f);
        if (wok) wv = *(const float4*)(Wp + (size_t)k0*400);
        __syncthreads();
        As[ak8+0][arow] = av0.x;
        As[ak8+1][arow] = av0.y;
        As[ak8+2][arow] = av0.z;
        As[ak8+3][arow] = av0.w;
        As[ak8+4][arow] = av1.x;
        As[ak8+5][arow] = av1.y;
        As[ak8+6][arow] = av1.z;
        As[ak8+7][arow] = av1.w;
        *(float4*)&Ws[wrow][wc4] = wv;
        __syncthreads();
        #pragma unroll
        for (int kk = 0; kk < 16; ++kk) {
            float4 b4  = *(const float4*)&Ws[kk][tx<<2];
            float4 a4a = *(const float4*)&As[kk][ty<<3];
            float4 a4b = *(const float4*)&As[kk][(ty<<3)+4];
            acc[0][0] += a4a.x*b4.x; acc[0][1] += a4a.x*b4.y; acc[0][2] += a4a.x*b4.z; acc[0][3] += a4a.x*b4.w;
            acc[1][0] += a4a.y*b4.x; acc[1][1] += a4a.y*b4.y; acc[1][2] += a4a.y*b4.z; acc[1][3] += a4a.y*b4.w;
            acc[2][0] += a4a.z*b4.x; acc[2][1] += a4a.z*b4.y; acc[2][2] += a4a.z*b4.z; acc[2][3] += a4a.z*b4.w;
            acc[3][0] += a4a.w*b4.x; acc[3][1] += a4a.w*b4.y; acc[3][2] += a4a.w*b4.z; acc[3][3] += a4a.w*b4.w;
            acc[4][0] += a4b.x*b4.x; acc[4][1] += a4b.x*b4.y; acc[4][2] += a4b.x*b4.z; acc[4][3] += a4b.x*b4.w;
            acc[5][0] += a4b.y*b4.x; acc[5][1] += a4b.y*b4.y; acc[5][2] += a4b.y*b4.z; acc[5][3] += a4b.y*b4.w;
            acc[6][0] += a4b.z*b4.x; acc[6][1] += a4b.z*b4.y; acc[6][2] += a4b.z*b4.z; acc[6][3] += a4b.z*b4.w;
            acc[7][0] += a4b.w*b4.x; acc[7][1] += a4b.w*b4.y; acc[7][2] += a4b.w*b4.z; acc[7][3] += a4b.w*b4.w;
        }
    }
    int gn = bn + (tx << 2);
    if (gn >= N) return;
    int gm = bm + (ty << 3);
    if (mode == 0) {
        #pragma unroll
        for (int i = 0; i < 8; ++i) {
            float4 v = make_float4(acc[i][0], acc[i][1], acc[i][2], acc[i][3]);
            *(float4*)&C[(size_t)(gm+i)*400 + gn] = v;
        }
    } else if (mode == 1) {
        float sa = sc[0], ca = sc[1], ss = sc[2], cs = sc[3];
        float4 cA = *(const float4*)&csA[gn];
        float4 cS = *(const float4*)&csS[gn];
        #pragma unroll
        for (int i = 0; i < 8; ++i) {
            float4 sv = *(const float4*)&S[(size_t)(gm+i)*400 + gn];
            float4 v;
            v.x = fmaxf(sa*acc[i][0] + ca*cA.x + ss*sv.x + cs*cS.x, 0.f);
            v.y = fmaxf(sa*acc[i][1] + ca*cA.y + ss*sv.y + cs*cS.y, 0.f);
            v.z = fmaxf(sa*acc[i][2] + ca*cA.z + ss*sv.z + cs*cS.z, 0.f);
            v.w = fmaxf(sa*acc[i][3] + ca*cA.w + ss*sv.w + cs*cS.w, 0.f);
            *(float4*)&C[(size_t)(gm+i)*400 + gn] = v;
        }
    } else {
        float sk = sc[4], ck = sc[5];
        float4 bv = *(const float4*)&bias[gn];
        #pragma unroll
        for (int i = 0; i < 8; ++i) {
            float4 v;
            v.x = sk*(acc[i][0] + bv.x) + ck;
            v.y = sk*(acc[i][1] + bv.y) + ck;
            v.z = sk*(acc[i][2] + bv.z) + ck;
            v.w = sk*(acc[i][3] + bv.w) + ck;
            *(float4*)&C[(size_t)(gm+i)*400 + gn] = v;
        }
    }
}

__global__ __launch_bounds__(256) void acc_logits_kernel(
    const float* __restrict__ node, const float* __restrict__ w, float* __restrict__ out)
{
    int wave = threadIdx.x >> 6, lane = threadIdx.x & 63;
    int row = blockIdx.x*4 + wave;
    const float* nr = node + (size_t)row*400;
    float s = 0.f;
    for (int j = lane; j < 400; j += 64) s += nr[j]*w[j];
    for (int o = 32; o > 0; o >>= 1) s += __shfl_down(s, o);
    if (lane == 0) out[row] += s;
}

extern "C" void kernel_launch(void* const* d_in, const int* in_sizes, int n_in,
                              void* d_out, int out_size, void* d_ws, size_t ws_size,
                              hipStream_t stream)
{
    const float* raw_dense  = (const float*)d_in[0];
    const int*   raw_sparse = (const int*)d_in[1];
    const float* emb   = (const float*)d_in[2];
    const float* Pd    = (const float*)d_in[3];
    const float* Ps    = (const float*)d_in[4];
    const float* Pb    = (const float*)d_in[5];
    const float* Wc    = (const float*)d_in[6];
    const float* bc    = (const float*)d_in[7];
    const float* clf_w = (const float*)d_in[8];
    const float* clf_b = (const float*)d_in[9];
    const float* a0 = (const float*)d_in[10];
    const float* a1 = (const float*)d_in[11];
    const float* a2 = (const float*)d_in[12];
    const float* a3 = (const float*)d_in[13];
    float* out = (float*)d_out;
    float* ws  = (float*)d_ws;

    float* scal    = ws;
    float* partial = ws + 32;                    // 2*EMB_BLOCKS
    float* csd     = partial + 2*EMB_BLOCKS;
    float* css     = csd + 400;
    float* csb     = css + 400;
    float* node0   = csb + 400 + 8;              // 16B aligned
    float* node1   = node0 + (size_t)8192*208;
    float* S1      = node1 + (size_t)8192*416;   // node1 @ P_sparse, reused by all 4 blocks
    float* hbuf    = S1    + (size_t)8192*400;
    float* nA      = hbuf  + (size_t)8192*400;
    float* nB      = nA    + (size_t)8192*400;

    prep_kernel<<<5,256,0,stream>>>(Pd,Ps,Pb,a0,a1,a2,a3,scal,csd,css,csb);
    embed_kernel<<<EMB_BLOCKS,256,0,stream>>>(raw_dense, raw_sparse, emb, node0, node1, partial);
    finalize_kernel<<<33,256,0,stream>>>(clf_b, partial, out);

    dim3 gg(7,64);
    // shared term: S1 = node1 @ P_sparse
    gemm_kernel<<<gg,256,0,stream>>>(node1, Ps, S1, 416, 400, 0, nullptr,nullptr,nullptr,nullptr,nullptr);
    // block 0
    gemm_kernel<<<gg,256,0,stream>>>(node0, Pd, hbuf, 208, 400, 1, S1, csd, css, scal+0, nullptr);
    gemm_kernel<<<gg,256,0,stream>>>(hbuf, Wc, nA, 400, 400, 2, nullptr,nullptr,nullptr, scal+0, bc);
    acc_logits_kernel<<<2048,256,0,stream>>>(nA, clf_w, out);
    // block 1
    gemm_kernel<<<gg,256,0,stream>>>(nA, Pb, hbuf, 400, 400, 1, S1, csb, css, scal+8, nullptr);
    gemm_kernel<<<gg,256,0,stream>>>(hbuf, Wc + (size_t)5*160000, nB, 400, 400, 2, nullptr,nullptr,nullptr, scal+8, bc + 5*400);
    acc_logits_kernel<<<2048,256,0,stream>>>(nB, clf_w + 400, out);
    // block 2
    gemm_kernel<<<gg,256,0,stream>>>(nB, Pb, hbuf, 400, 400, 1, S1, csb, css, scal+16, nullptr);
    gemm_kernel<<<gg,256,0,stream>>>(hbuf, Wc + (size_t)10*160000, nA, 400, 400, 2, nullptr,nullptr,nullptr, scal+16, bc + 10*400);
    acc_logits_kernel<<<2048,256,0,stream>>>(nA, clf_w + 800, out);
    // block 3
    gemm_kernel<<<gg,256,0,stream>>>(nA, Pb, hbuf, 400, 400, 1, S1, csb, css, scal+24, nullptr);
    gemm_kernel<<<gg,256,0,stream>>>(hbuf, Wc + (size_t)15*160000, nB, 400, 400, 2, nullptr,nullptr,nullptr, scal+24, bc + 15*400);
    acc_logits_kernel<<<2048,256,0,stream>>>(nB, clf_w + 1200, out);
}

// Round 3
// 558.918 us; speedup vs baseline: 1.5274x; 1.2054x over previous
//
#include <hip/hip_runtime.h>
#include <cstddef>

// DynamicNetwork via split-bf16 MFMA (hi/lo decomposition, 3 MFMA per product).
// All activations/weights carried as bf16 hi+lo planes; value = hi+lo (err ~2^-18).
// Mode-1 GEMMs use concatenated-K: h = relu([nodeX | node1] @ [s*P ; s'*Ps] + cvec).

typedef short short8 __attribute__((ext_vector_type(8)));
typedef float floatx16 __attribute__((ext_vector_type(16)));

#define EMB_BLOCKS 832

__device__ __forceinline__ unsigned short f2bf(float f) {
    unsigned int u = __float_as_uint(f);
    u += 0x7fffu + ((u >> 16) & 1u);
    return (unsigned short)(u >> 16);
}
__device__ __forceinline__ float bf2f(unsigned short h) {
    return __uint_as_float((unsigned int)h << 16);
}
__device__ __forceinline__ void split2(float v, unsigned short& h, unsigned short& l) {
    h = f2bf(v);
    l = f2bf(v - bf2f(h));
}

// ---------------- prep1: column sums + alpha scalars ----------------
__global__ __launch_bounds__(256) void prep1_kernel(
    const float* __restrict__ Pd, const float* __restrict__ Ps, const float* __restrict__ Pb,
    const float* __restrict__ a0, const float* __restrict__ a1,
    const float* __restrict__ a2, const float* __restrict__ a3,
    float* __restrict__ scal,
    float* __restrict__ csd, float* __restrict__ css, float* __restrict__ csb)
{
    int gid = blockIdx.x * 256 + threadIdx.x;
    if (gid < 400) {
        float s = 0.f;
        for (int k = 0; k < 208; ++k) s += Pd[k*400 + gid];
        csd[gid] = s;
    } else if (gid < 800) {
        int j = gid - 400; float s = 0.f;
        for (int k = 0; k < 416; ++k) s += Ps[k*400 + j];
        css[j] = s;
    } else if (gid < 1200) {
        int j = gid - 800; float s = 0.f;
        for (int k = 0; k < 400; ++k) s += Pb[k*400 + j];
        csb[j] = s;
    } else if (gid < 1204) {
        int i = gid - 1200;
        const float* a = (i==0) ? a0 : (i==1) ? a1 : (i==2) ? a2 : a3;
        int np = 2 + i;
        float sum1 = 0.f, sum2 = 0.f, sumc = 0.f;
        for (int j = 0; j < np; ++j) { sum1 += a[j]; sum2 += a[np+j]; }
        for (int j = 0; j < 4; ++j) sumc += a[2*np+j];
        int i1 = (i==0) ? 0 : 1;
        int i2 = i + 1;
        int kk = i;
        float s1 = a[i1],      c1 = sum1 - s1;   // x1 term (node i1)
        float s2 = a[np+i2],   c2 = sum2 - s2;   // x2 term (node i2)
        float sk = a[2*np+kk], ck = sumc - sk;
        float* sl = scal + i*8;
        // [0,1]=A-segment (seg1) scalars, [2,3]=Ps-segment scalars, [4,5]=sk,ck
        if (i == 0) { sl[0]=s1; sl[1]=c1; sl[2]=s2; sl[3]=c2; }  // seg1=node0@Pd
        else        { sl[0]=s2; sl[1]=c2; sl[2]=s1; sl[3]=c1; }  // seg1=node_{i+1}@Pb
        sl[4] = sk; sl[5] = ck;
    }
}

// ---------------- prep2: transpose + scale + split weights -> [448][Kp] bf16 hi|lo planes
__global__ __launch_bounds__(256) void prep2_kernel(
    const float* __restrict__ Pd, const float* __restrict__ Ps,
    const float* __restrict__ Pb, const float* __restrict__ Wc,
    const float* __restrict__ scal,
    unsigned short* __restrict__ w0, unsigned short* __restrict__ w1,
    unsigned short* __restrict__ w2, unsigned short* __restrict__ w3,
    unsigned short* __restrict__ v0, unsigned short* __restrict__ v1,
    unsigned short* __restrict__ v2, unsigned short* __restrict__ v3)
{
    int z = blockIdx.z;
    int Kp, KA; const float *sA, *sB; float sc1, sc2; unsigned short* dst;
    if (z < 4) {
        Kp = (z==0) ? 624 : 816; KA = (z==0) ? 208 : 400;
        sA = (z==0) ? Pd : Pb; sB = Ps;
        sc1 = scal[z*8+0]; sc2 = scal[z*8+2];
        dst = (z==0) ? w0 : (z==1) ? w1 : (z==2) ? w2 : w3;
    } else {
        int i = z - 4;
        Kp = 400; KA = 400;
        sA = Wc + (size_t)i*5*160000; sB = nullptr;
        sc1 = scal[i*8+4]; sc2 = 0.f;
        dst = (i==0) ? v0 : (i==1) ? v1 : (i==2) ? v2 : v3;
    }
    int ktiles = (Kp + 63) >> 6;
    if ((int)blockIdx.y >= ktiles) return;
    int k0 = blockIdx.y * 64, n0 = blockIdx.x * 64;
    __shared__ float T[64][65];
    int t = threadIdx.x;
    {
        int kr = t >> 2, c0 = (t & 3) * 16;
        int gk = k0 + kr;
        bool kok = gk < Kp;
        const float* src; int srow; float sc;
        if (gk < KA) { src = sA; srow = gk; sc = sc1; }
        else         { src = sB; srow = gk - KA; sc = sc2; }
        for (int j = 0; j < 16; j += 4) {
            int n = n0 + c0 + j;
            float4 v = make_float4(0.f,0.f,0.f,0.f);
            if (kok && n < 400) v = *(const float4*)&src[(size_t)srow*400 + n];
            T[kr][c0+j+0] = v.x * sc;
            T[kr][c0+j+1] = v.y * sc;
            T[kr][c0+j+2] = v.z * sc;
            T[kr][c0+j+3] = v.w * sc;
        }
    }
    __syncthreads();
    {
        int nr = t >> 2, kc0 = (t & 3) * 16;
        int gn = n0 + nr;
        int gk0 = k0 + kc0;
        if (gk0 >= Kp) return;
        unsigned short hb[16], lb[16];
        for (int j = 0; j < 16; ++j) {
            float v = (gn < 400) ? T[kc0+j][nr] : 0.f;
            split2(v, hb[j], lb[j]);
        }
        unsigned short* dh = dst + (size_t)gn*Kp + gk0;
        unsigned short* dl = dst + (size_t)448*Kp + (size_t)gn*Kp + gk0;
        *(uint4*)&dh[0] = *(uint4*)&hb[0]; *(uint4*)&dh[8] = *(uint4*)&hb[8];
        *(uint4*)&dl[0] = *(uint4*)&lb[0]; *(uint4*)&dl[8] = *(uint4*)&lb[8];
    }
}

// ---------------- prep3: epilogue vectors cvec/dvec ----------------
__global__ __launch_bounds__(256) void prep3_kernel(
    const float* __restrict__ scal,
    const float* __restrict__ csd, const float* __restrict__ css, const float* __restrict__ csb,
    const float* __restrict__ bc,
    float* __restrict__ cv, float* __restrict__ dv)
{
    int i = blockIdx.x;
    for (int j = threadIdx.x; j < 448; j += 256) {
        float c = 0.f, d = 0.f;
        if (j < 400) {
            const float* cs1 = (i==0) ? csd : csb;
            c = scal[i*8+1]*cs1[j] + scal[i*8+3]*css[j];
            d = scal[i*8+4]*bc[i*5*400 + j] + scal[i*8+5];
        }
        cv[i*448 + j] = c;
        dv[i*448 + j] = d;
    }
}

// ---------------- embed: node0/node1 bf16 hi/lo planes + sumsq partials ----------------
__global__ __launch_bounds__(256) void embed_kernel(
    const float* __restrict__ rd, const int* __restrict__ rs,
    const float* __restrict__ emb,
    unsigned short* __restrict__ n0h, unsigned short* __restrict__ n0l,
    unsigned short* __restrict__ n1h, unsigned short* __restrict__ n1l,
    float* __restrict__ partial)
{
    int tid0 = blockIdx.x*256 + threadIdx.x;
    int nth = gridDim.x*256;
    float ssq = 0.f, dsq = 0.f;
    for (int it = tid0; it < 8192*26; it += nth) {
        int b = it / 26, s = it - b*26;
        int row = 13 + 50000*s + rs[b*26 + s];
        const float* e = emb + (size_t)row*16;
        float4 e0 = *(const float4*)&e[0], e1 = *(const float4*)&e[4];
        float4 e2 = *(const float4*)&e[8], e3 = *(const float4*)&e[12];
        float vv[16] = {e0.x,e0.y,e0.z,e0.w, e1.x,e1.y,e1.z,e1.w,
                        e2.x,e2.y,e2.z,e2.w, e3.x,e3.y,e3.z,e3.w};
        unsigned short hb[16], lb[16];
        for (int j = 0; j < 16; ++j) { ssq += vv[j]*vv[j]; split2(vv[j], hb[j], lb[j]); }
        size_t off = (size_t)b*416 + s*16;
        *(uint4*)&n1h[off] = *(uint4*)&hb[0]; *(uint4*)&n1h[off+8] = *(uint4*)&hb[8];
        *(uint4*)&n1l[off] = *(uint4*)&lb[0]; *(uint4*)&n1l[off+8] = *(uint4*)&lb[8];
    }
    for (int it = tid0; it < 8192*13; it += nth) {
        int b = it / 13, f = it - b*13;
        float sc = rd[b*13 + f];
        const float* e = emb + (size_t)f*16;
        float4 e0 = *(const float4*)&e[0], e1 = *(const float4*)&e[4];
        float4 e2 = *(const float4*)&e[8], e3 = *(const float4*)&e[12];
        float vv[16] = {e0.x,e0.y,e0.z,e0.w, e1.x,e1.y,e1.z,e1.w,
                        e2.x,e2.y,e2.z,e2.w, e3.x,e3.y,e3.z,e3.w};
        unsigned short hb[16], lb[16];
        for (int j = 0; j < 16; ++j) { float v = vv[j]*sc; dsq += v*v; split2(v, hb[j], lb[j]); }
        size_t off = (size_t)b*208 + f*16;
        *(uint4*)&n0h[off] = *(uint4*)&hb[0]; *(uint4*)&n0h[off+8] = *(uint4*)&hb[8];
        *(uint4*)&n0l[off] = *(uint4*)&lb[0]; *(uint4*)&n0l[off+8] = *(uint4*)&lb[8];
    }
    for (int o = 32; o > 0; o >>= 1) { ssq += __shfl_down(ssq, o); dsq += __shfl_down(dsq, o); }
    __shared__ float red[8];
    int wave = threadIdx.x >> 6, lane = threadIdx.x & 63;
    if (lane == 0) { red[wave] = dsq; red[4+wave] = ssq; }
    __syncthreads();
    if (threadIdx.x == 0) {
        partial[blockIdx.x*2]   = red[0]+red[1]+red[2]+red[3];
        partial[blockIdx.x*2+1] = red[4]+red[5]+red[6]+red[7];
    }
}

__global__ __launch_bounds__(256) void finalize_kernel(
    const float* __restrict__ clf_b, const float* __restrict__ partial, float* __restrict__ out)
{
    if (blockIdx.x < 32) {
        out[blockIdx.x*256 + threadIdx.x] = clf_b[0];
        return;
    }
    float d = 0.f, s = 0.f;
    for (int i = threadIdx.x; i < EMB_BLOCKS; i += 256) { d += partial[2*i]; s += partial[2*i+1]; }
    for (int o = 32; o > 0; o >>= 1) { d += __shfl_down(d, o); s += __shfl_down(s, o); }
    __shared__ float red[8];
    int wave = threadIdx.x >> 6, lane = threadIdx.x & 63;
    if (lane == 0) { red[wave] = d; red[4+wave] = s; }
    __syncthreads();
    if (threadIdx.x == 0) {
        float dd = red[0]+red[1]+red[2]+red[3];
        float ss = red[4]+red[5]+red[6]+red[7];
        out[8192] = 1e-5f * (sqrtf(dd) + sqrtf(ss));
    }
}

// ---------------- split-bf16 MFMA GEMM ----------------
// C[8192 x 400] = A'[8192 x Kp] @ B[Kp x 400] + vec[j], optional relu.
// A' = [seg1 (stride sA, cols 0..KA) | seg2=node1 (stride 416, cols KA..Kp)]
// B given pre-transposed+scaled+split: planes [448][Kp] (hi then lo), zero-padded rows n>=400.
// Block tile 64x64, 4 waves each 32x32 via v_mfma_f32_32x32x16_bf16, 3 mfma per k16 (hh,hl,lh).
__global__ __launch_bounds__(256) void mfma_gemm(
    const unsigned short* __restrict__ a1h, const unsigned short* __restrict__ a1l, int sA, int KA,
    const unsigned short* __restrict__ a2h, const unsigned short* __restrict__ a2l,
    const unsigned short* __restrict__ bph,  // hi plane; lo plane at +448*Kp
    int Kp, const float* __restrict__ vec, int relu,
    unsigned short* __restrict__ ch, unsigned short* __restrict__ cl)
{
    __shared__ unsigned short As[2][64*72];  // [hi/lo][row*72 + k], stride 72 -> bank-uniform b128
    __shared__ unsigned short Bs[2][64*72];
    const unsigned short* bpl = bph + (size_t)448*Kp;
    int tid = threadIdx.x;
    int bm = blockIdx.y * 64, bn = blockIdx.x * 64;
    int row = tid & 63, ks = tid >> 6;       // staging: 64 rows x 4 k16-slots
    int w = tid >> 6, lane = tid & 63;
    int moff = (w & 1) * 32, noff = (w >> 1) * 32;
    int r31 = lane & 31, hh = lane >> 5;
    floatx16 acc;
    for (int i = 0; i < 16; ++i) acc[i] = 0.f;
    int nk16 = Kp >> 4;
    int nchunks = (Kp + 63) >> 6;
    int fragA = (moff + r31)*72 + hh*8;
    int fragB = (noff + r31)*72 + hh*8;
    int lbase = row*72 + ks*16;
    for (int c = 0; c < nchunks; ++c) {
        int kg = (c << 2) + ks;
        int kb = kg << 4;
        uint4 ah0 = make_uint4(0,0,0,0), ah1 = ah0, al0 = ah0, al1 = ah0;
        uint4 bh0 = ah0, bh1 = ah0, bl0 = ah0, bl1 = ah0;
        if (kg < nk16) {
            const unsigned short *ph, *pl;
            if (kb < KA) {
                ph = a1h + (size_t)(bm+row)*sA + kb;
                pl = a1l + (size_t)(bm+row)*sA + kb;
            } else {
                ph = a2h + (size_t)(bm+row)*416 + (kb - KA);
                pl = a2l + (size_t)(bm+row)*416 + (kb - KA);
            }
            ah0 = *(const uint4*)ph;     ah1 = *(const uint4*)(ph+8);
            al0 = *(const uint4*)pl;     al1 = *(const uint4*)(pl+8);
            const unsigned short* qh = bph + (size_t)(bn+row)*Kp + kb;
            const unsigned short* ql = bpl + (size_t)(bn+row)*Kp + kb;
            bh0 = *(const uint4*)qh;     bh1 = *(const uint4*)(qh+8);
            bl0 = *(const uint4*)ql;     bl1 = *(const uint4*)(ql+8);
        }
        __syncthreads();
        *(uint4*)&As[0][lbase]   = ah0;  *(uint4*)&As[0][lbase+8] = ah1;
        *(uint4*)&As[1][lbase]   = al0;  *(uint4*)&As[1][lbase+8] = al1;
        *(uint4*)&Bs[0][lbase]   = bh0;  *(uint4*)&Bs[0][lbase+8] = bh1;
        *(uint4*)&Bs[1][lbase]   = bl0;  *(uint4*)&Bs[1][lbase+8] = bl1;
        __syncthreads();
        #pragma unroll
        for (int s = 0; s < 4; ++s) {
            short8 fah = *(const short8*)&As[0][fragA + s*16];
            short8 fal = *(const short8*)&As[1][fragA + s*16];
            short8 fbh = *(const short8*)&Bs[0][fragB + s*16];
            short8 fbl = *(const short8*)&Bs[1][fragB + s*16];
            acc = __builtin_amdgcn_mfma_f32_32x32x16_bf16(fah, fbh, acc, 0, 0, 0);
            acc = __builtin_amdgcn_mfma_f32_32x32x16_bf16(fah, fbl, acc, 0, 0, 0);
            acc = __builtin_amdgcn_mfma_f32_32x32x16_bf16(fal, fbh, acc, 0, 0, 0);
        }
    }
    // epilogue: C/D layout col=lane&31, row=(reg&3)+8*(reg>>2)+4*(lane>>5)
    int gn = bn + noff + r31;
    if (gn >= 400) return;
    float vc = vec[gn];
    #pragma unroll
    for (int r = 0; r < 16; ++r) {
        int rr = (r & 3) + 8*(r >> 2) + 4*hh;
        int gm = bm + moff + rr;
        float v = acc[r] + vc;
        if (relu) v = fmaxf(v, 0.f);
        unsigned short h16, l16;
        split2(v, h16, l16);
        ch[(size_t)gm*400 + gn] = h16;
        cl[(size_t)gm*400 + gn] = l16;
    }
}

// ---------------- logits accumulation from hi/lo planes ----------------
__global__ __launch_bounds__(256) void acc_logits_kernel(
    const unsigned short* __restrict__ nh, const unsigned short* __restrict__ nl,
    const float* __restrict__ w, float* __restrict__ out)
{
    int wave = threadIdx.x >> 6, lane = threadIdx.x & 63;
    int row = blockIdx.x*4 + wave;
    const unsigned short* ph = nh + (size_t)row*400;
    const unsigned short* pl = nl + (size_t)row*400;
    float s = 0.f;
    #pragma unroll
    for (int it = 0; it < 4; ++it) {
        int j = it*128 + lane*2;
        if (j < 400) {
            unsigned int h2 = *(const unsigned int*)&ph[j];
            unsigned int l2 = *(const unsigned int*)&pl[j];
            float v0 = bf2f((unsigned short)(h2 & 0xffff)) + bf2f((unsigned short)(l2 & 0xffff));
            float v1 = bf2f((unsigned short)(h2 >> 16))    + bf2f((unsigned short)(l2 >> 16));
            s += v0*w[j] + v1*w[j+1];
        }
    }
    for (int o = 32; o > 0; o >>= 1) s += __shfl_down(s, o);
    if (lane == 0) out[row] += s;
}

// ---------------- host ----------------
static inline size_t align16(size_t x) { return (x + 15) & ~(size_t)15; }

extern "C" void kernel_launch(void* const* d_in, const int* in_sizes, int n_in,
                              void* d_out, int out_size, void* d_ws, size_t ws_size,
                              hipStream_t stream)
{
    const float* raw_dense  = (const float*)d_in[0];
    const int*   raw_sparse = (const int*)d_in[1];
    const float* emb   = (const float*)d_in[2];
    const float* Pd    = (const float*)d_in[3];
    const float* Ps    = (const float*)d_in[4];
    const float* Pb    = (const float*)d_in[5];
    const float* Wc    = (const float*)d_in[6];
    const float* bc    = (const float*)d_in[7];
    const float* clf_w = (const float*)d_in[8];
    const float* clf_b = (const float*)d_in[9];
    const float* a0 = (const float*)d_in[10];
    const float* a1 = (const float*)d_in[11];
    const float* a2 = (const float*)d_in[12];
    const float* a3 = (const float*)d_in[13];
    float* out = (float*)d_out;

    char* p = (char*)d_ws;
    auto alloc = [&](size_t bytes) { char* r = p; p += align16(bytes); return r; };

    float* scal    = (float*)alloc(32*4);
    float* partial = (float*)alloc(2*EMB_BLOCKS*4);
    float* csd     = (float*)alloc(400*4);
    float* css     = (float*)alloc(400*4);
    float* csb     = (float*)alloc(400*4);
    float* cv      = (float*)alloc(4*448*4);
    float* dv      = (float*)alloc(4*448*4);
    unsigned short* w0 = (unsigned short*)alloc((size_t)2*448*624*2);
    unsigned short* w1 = (unsigned short*)alloc((size_t)2*448*816*2);
    unsigned short* w2 = (unsigned short*)alloc((size_t)2*448*816*2);
    unsigned short* w3 = (unsigned short*)alloc((size_t)2*448*816*2);
    unsigned short* v0 = (unsigned short*)alloc((size_t)2*448*400*2);
    unsigned short* v1 = (unsigned short*)alloc((size_t)2*448*400*2);
    unsigned short* v2 = (unsigned short*)alloc((size_t)2*448*400*2);
    unsigned short* v3 = (unsigned short*)alloc((size_t)2*448*400*2);
    unsigned short* n0h = (unsigned short*)alloc((size_t)8192*208*2);
    unsigned short* n0l = (unsigned short*)alloc((size_t)8192*208*2);
    unsigned short* n1h = (unsigned short*)alloc((size_t)8192*416*2);
    unsigned short* n1l = (unsigned short*)alloc((size_t)8192*416*2);
    unsigned short* hh  = (unsigned short*)alloc((size_t)8192*400*2);
    unsigned short* hl  = (unsigned short*)alloc((size_t)8192*400*2);
    unsigned short* nAh = (unsigned short*)alloc((size_t)8192*400*2);
    unsigned short* nAl = (unsigned short*)alloc((size_t)8192*400*2);
    unsigned short* nBh = (unsigned short*)alloc((size_t)8192*400*2);
    unsigned short* nBl = (unsigned short*)alloc((size_t)8192*400*2);

    prep1_kernel<<<5,256,0,stream>>>(Pd,Ps,Pb,a0,a1,a2,a3,scal,csd,css,csb);
    embed_kernel<<<EMB_BLOCKS,256,0,stream>>>(raw_dense, raw_sparse, emb, n0h,n0l,n1h,n1l, partial);
    finalize_kernel<<<33,256,0,stream>>>(clf_b, partial, out);
    prep2_kernel<<<dim3(7,13,8),256,0,stream>>>(Pd,Ps,Pb,Wc,scal,w0,w1,w2,w3,v0,v1,v2,v3);
    prep3_kernel<<<4,256,0,stream>>>(scal,csd,css,csb,bc,cv,dv);

    dim3 gg(7,128);
    // block 0: h = relu([node0|node1] @ w0 + cv0); node2 = h @ v0 + dv0
    mfma_gemm<<<gg,256,0,stream>>>(n0h,n0l,208,208, n1h,n1l, w0, 624, cv+0,   1, hh,hl);
    mfma_gemm<<<gg,256,0,stream>>>(hh,hl,400,400, nullptr,nullptr, v0, 400, dv+0,   0, nAh,nAl);
    acc_logits_kernel<<<2048,256,0,stream>>>(nAh,nAl, clf_w, out);
    // block 1
    mfma_gemm<<<gg,256,0,stream>>>(nAh,nAl,400,400, n1h,n1l, w1, 816, cv+448, 1, hh,hl);
    mfma_gemm<<<gg,256,0,stream>>>(hh,hl,400,400, nullptr,nullptr, v1, 400, dv+448, 0, nBh,nBl);
    acc_logits_kernel<<<2048,256,0,stream>>>(nBh,nBl, clf_w+400, out);
    // block 2
    mfma_gemm<<<gg,256,0,stream>>>(nBh,nBl,400,400, n1h,n1l, w2, 816, cv+896, 1, hh,hl);
    mfma_gemm<<<gg,256,0,stream>>>(hh,hl,400,400, nullptr,nullptr, v2, 400, dv+896, 0, nAh,nAl);
    acc_logits_kernel<<<2048,256,0,stream>>>(nAh,nAl, clf_w+800, out);
    // block 3
    mfma_gemm<<<gg,256,0,stream>>>(nAh,nAl,400,400, n1h,n1l, w3, 816, cv+1344, 1, hh,hl);
    mfma_gemm<<<gg,256,0,stream>>>(hh,hl,400,400, nullptr,nullptr, v3, 400, dv+1344, 0, nBh,nBl);
    acc_logits_kernel<<<2048,256,0,stream>>>(nBh,nBl, clf_w+1200, out);
}

// Round 4
// 453.005 us; speedup vs baseline: 1.8845x; 1.2338x over previous
//
#include <hip/hip_runtime.h>
#include <cstddef>

// DynamicNetwork via split-bf16 MFMA (hi/lo decomposition, 3 MFMA per product).
// R4: XCD-aware block swizzle (same-row tiles share one XCD's L2),
//     register-prefetch pipelined K-loop, logits fused into mode-2 epilogue.

typedef short short8 __attribute__((ext_vector_type(8)));
typedef float floatx16 __attribute__((ext_vector_type(16)));

#define EMB_BLOCKS 832

__device__ __forceinline__ unsigned short f2bf(float f) {
    unsigned int u = __float_as_uint(f);
    u += 0x7fffu + ((u >> 16) & 1u);
    return (unsigned short)(u >> 16);
}
__device__ __forceinline__ float bf2f(unsigned short h) {
    return __uint_as_float((unsigned int)h << 16);
}
__device__ __forceinline__ void split2(float v, unsigned short& h, unsigned short& l) {
    h = f2bf(v);
    l = f2bf(v - bf2f(h));
}

// ---------------- prep1: column sums + alpha scalars ----------------
__global__ __launch_bounds__(256) void prep1_kernel(
    const float* __restrict__ Pd, const float* __restrict__ Ps, const float* __restrict__ Pb,
    const float* __restrict__ a0, const float* __restrict__ a1,
    const float* __restrict__ a2, const float* __restrict__ a3,
    float* __restrict__ scal,
    float* __restrict__ csd, float* __restrict__ css, float* __restrict__ csb)
{
    int gid = blockIdx.x * 256 + threadIdx.x;
    if (gid < 400) {
        float s = 0.f;
        for (int k = 0; k < 208; ++k) s += Pd[k*400 + gid];
        csd[gid] = s;
    } else if (gid < 800) {
        int j = gid - 400; float s = 0.f;
        for (int k = 0; k < 416; ++k) s += Ps[k*400 + j];
        css[j] = s;
    } else if (gid < 1200) {
        int j = gid - 800; float s = 0.f;
        for (int k = 0; k < 400; ++k) s += Pb[k*400 + j];
        csb[j] = s;
    } else if (gid < 1204) {
        int i = gid - 1200;
        const float* a = (i==0) ? a0 : (i==1) ? a1 : (i==2) ? a2 : a3;
        int np = 2 + i;
        float sum1 = 0.f, sum2 = 0.f, sumc = 0.f;
        for (int j = 0; j < np; ++j) { sum1 += a[j]; sum2 += a[np+j]; }
        for (int j = 0; j < 4; ++j) sumc += a[2*np+j];
        int i1 = (i==0) ? 0 : 1;
        int i2 = i + 1;
        int kk = i;
        float s1 = a[i1],      c1 = sum1 - s1;
        float s2 = a[np+i2],   c2 = sum2 - s2;
        float sk = a[2*np+kk], ck = sumc - sk;
        float* sl = scal + i*8;
        if (i == 0) { sl[0]=s1; sl[1]=c1; sl[2]=s2; sl[3]=c2; }
        else        { sl[0]=s2; sl[1]=c2; sl[2]=s1; sl[3]=c1; }
        sl[4] = sk; sl[5] = ck;
    }
}

// ---------------- prep2: transpose + scale + split weights -> [448][Kp] bf16 hi|lo planes
__global__ __launch_bounds__(256) void prep2_kernel(
    const float* __restrict__ Pd, const float* __restrict__ Ps,
    const float* __restrict__ Pb, const float* __restrict__ Wc,
    const float* __restrict__ scal,
    unsigned short* __restrict__ w0, unsigned short* __restrict__ w1,
    unsigned short* __restrict__ w2, unsigned short* __restrict__ w3,
    unsigned short* __restrict__ v0, unsigned short* __restrict__ v1,
    unsigned short* __restrict__ v2, unsigned short* __restrict__ v3)
{
    int z = blockIdx.z;
    int Kp, KA; const float *sA, *sB; float sc1, sc2; unsigned short* dst;
    if (z < 4) {
        Kp = (z==0) ? 624 : 816; KA = (z==0) ? 208 : 400;
        sA = (z==0) ? Pd : Pb; sB = Ps;
        sc1 = scal[z*8+0]; sc2 = scal[z*8+2];
        dst = (z==0) ? w0 : (z==1) ? w1 : (z==2) ? w2 : w3;
    } else {
        int i = z - 4;
        Kp = 400; KA = 400;
        sA = Wc + (size_t)i*5*160000; sB = nullptr;
        sc1 = scal[i*8+4]; sc2 = 0.f;
        dst = (i==0) ? v0 : (i==1) ? v1 : (i==2) ? v2 : v3;
    }
    int ktiles = (Kp + 63) >> 6;
    if ((int)blockIdx.y >= ktiles) return;
    int k0 = blockIdx.y * 64, n0 = blockIdx.x * 64;
    __shared__ float T[64][65];
    int t = threadIdx.x;
    {
        int kr = t >> 2, c0 = (t & 3) * 16;
        int gk = k0 + kr;
        bool kok = gk < Kp;
        const float* src; int srow; float sc;
        if (gk < KA) { src = sA; srow = gk; sc = sc1; }
        else         { src = sB; srow = gk - KA; sc = sc2; }
        for (int j = 0; j < 16; j += 4) {
            int n = n0 + c0 + j;
            float4 v = make_float4(0.f,0.f,0.f,0.f);
            if (kok && n < 400) v = *(const float4*)&src[(size_t)srow*400 + n];
            T[kr][c0+j+0] = v.x * sc;
            T[kr][c0+j+1] = v.y * sc;
            T[kr][c0+j+2] = v.z * sc;
            T[kr][c0+j+3] = v.w * sc;
        }
    }
    __syncthreads();
    {
        int nr = t >> 2, kc0 = (t & 3) * 16;
        int gn = n0 + nr;
        int gk0 = k0 + kc0;
        if (gk0 >= Kp) return;
        unsigned short hb[16], lb[16];
        for (int j = 0; j < 16; ++j) {
            float v = (gn < 400) ? T[kc0+j][nr] : 0.f;
            split2(v, hb[j], lb[j]);
        }
        unsigned short* dh = dst + (size_t)gn*Kp + gk0;
        unsigned short* dl = dst + (size_t)448*Kp + (size_t)gn*Kp + gk0;
        *(uint4*)&dh[0] = *(uint4*)&hb[0]; *(uint4*)&dh[8] = *(uint4*)&hb[8];
        *(uint4*)&dl[0] = *(uint4*)&lb[0]; *(uint4*)&dl[8] = *(uint4*)&lb[8];
    }
}

// ---------------- prep3: epilogue vectors cvec/dvec ----------------
__global__ __launch_bounds__(256) void prep3_kernel(
    const float* __restrict__ scal,
    const float* __restrict__ csd, const float* __restrict__ css, const float* __restrict__ csb,
    const float* __restrict__ bc,
    float* __restrict__ cv, float* __restrict__ dv)
{
    int i = blockIdx.x;
    for (int j = threadIdx.x; j < 448; j += 256) {
        float c = 0.f, d = 0.f;
        if (j < 400) {
            const float* cs1 = (i==0) ? csd : csb;
            c = scal[i*8+1]*cs1[j] + scal[i*8+3]*css[j];
            d = scal[i*8+4]*bc[i*5*400 + j] + scal[i*8+5];
        }
        cv[i*448 + j] = c;
        dv[i*448 + j] = d;
    }
}

// ---------------- embed: node0/node1 bf16 hi/lo planes + sumsq partials ----------------
__global__ __launch_bounds__(256) void embed_kernel(
    const float* __restrict__ rd, const int* __restrict__ rs,
    const float* __restrict__ emb,
    unsigned short* __restrict__ n0h, unsigned short* __restrict__ n0l,
    unsigned short* __restrict__ n1h, unsigned short* __restrict__ n1l,
    float* __restrict__ partial)
{
    int tid0 = blockIdx.x*256 + threadIdx.x;
    int nth = gridDim.x*256;
    float ssq = 0.f, dsq = 0.f;
    for (int it = tid0; it < 8192*26; it += nth) {
        int b = it / 26, s = it - b*26;
        int row = 13 + 50000*s + rs[b*26 + s];
        const float* e = emb + (size_t)row*16;
        float4 e0 = *(const float4*)&e[0], e1 = *(const float4*)&e[4];
        float4 e2 = *(const float4*)&e[8], e3 = *(const float4*)&e[12];
        float vv[16] = {e0.x,e0.y,e0.z,e0.w, e1.x,e1.y,e1.z,e1.w,
                        e2.x,e2.y,e2.z,e2.w, e3.x,e3.y,e3.z,e3.w};
        unsigned short hb[16], lb[16];
        for (int j = 0; j < 16; ++j) { ssq += vv[j]*vv[j]; split2(vv[j], hb[j], lb[j]); }
        size_t off = (size_t)b*416 + s*16;
        *(uint4*)&n1h[off] = *(uint4*)&hb[0]; *(uint4*)&n1h[off+8] = *(uint4*)&hb[8];
        *(uint4*)&n1l[off] = *(uint4*)&lb[0]; *(uint4*)&n1l[off+8] = *(uint4*)&lb[8];
    }
    for (int it = tid0; it < 8192*13; it += nth) {
        int b = it / 13, f = it - b*13;
        float sc = rd[b*13 + f];
        const float* e = emb + (size_t)f*16;
        float4 e0 = *(const float4*)&e[0], e1 = *(const float4*)&e[4];
        float4 e2 = *(const float4*)&e[8], e3 = *(const float4*)&e[12];
        float vv[16] = {e0.x,e0.y,e0.z,e0.w, e1.x,e1.y,e1.z,e1.w,
                        e2.x,e2.y,e2.z,e2.w, e3.x,e3.y,e3.z,e3.w};
        unsigned short hb[16], lb[16];
        for (int j = 0; j < 16; ++j) { float v = vv[j]*sc; dsq += v*v; split2(v, hb[j], lb[j]); }
        size_t off = (size_t)b*208 + f*16;
        *(uint4*)&n0h[off] = *(uint4*)&hb[0]; *(uint4*)&n0h[off+8] = *(uint4*)&hb[8];
        *(uint4*)&n0l[off] = *(uint4*)&lb[0]; *(uint4*)&n0l[off+8] = *(uint4*)&lb[8];
    }
    for (int o = 32; o > 0; o >>= 1) { ssq += __shfl_down(ssq, o); dsq += __shfl_down(dsq, o); }
    __shared__ float red[8];
    int wave = threadIdx.x >> 6, lane = threadIdx.x & 63;
    if (lane == 0) { red[wave] = dsq; red[4+wave] = ssq; }
    __syncthreads();
    if (threadIdx.x == 0) {
        partial[blockIdx.x*2]   = red[0]+red[1]+red[2]+red[3];
        partial[blockIdx.x*2+1] = red[4]+red[5]+red[6]+red[7];
    }
}

__global__ __launch_bounds__(256) void finalize_kernel(
    const float* __restrict__ clf_b, const float* __restrict__ partial, float* __restrict__ out)
{
    if (blockIdx.x < 32) {
        out[blockIdx.x*256 + threadIdx.x] = clf_b[0];
        return;
    }
    float d = 0.f, s = 0.f;
    for (int i = threadIdx.x; i < EMB_BLOCKS; i += 256) { d += partial[2*i]; s += partial[2*i+1]; }
    for (int o = 32; o > 0; o >>= 1) { d += __shfl_down(d, o); s += __shfl_down(s, o); }
    __shared__ float red[8];
    int wave = threadIdx.x >> 6, lane = threadIdx.x & 63;
    if (lane == 0) { red[wave] = d; red[4+wave] = s; }
    __syncthreads();
    if (threadIdx.x == 0) {
        float dd = red[0]+red[1]+red[2]+red[3];
        float ss = red[4]+red[5]+red[6]+red[7];
        out[8192] = 1e-5f * (sqrtf(dd) + sqrtf(ss));
    }
}

// ---------------- split-bf16 MFMA GEMM ----------------
// Grid: 896 1-D blocks, XCD-swizzled: xcd=f&7 owns y-tiles [16*xcd,16*xcd+16) x all 7 x-tiles
// so blocks sharing A rows share one XCD's L2.
// Pipelined: chunk c+1 global loads issue before MFMA(c); LDS write waits under next barrier.
// If lw != null: fused logits (sum_j C[b][j]*lw[j]) atomically added into lout[b].
__global__ __launch_bounds__(256) void mfma_gemm(
    const unsigned short* __restrict__ a1h, const unsigned short* __restrict__ a1l, int sA, int KA,
    const unsigned short* __restrict__ a2h, const unsigned short* __restrict__ a2l,
    const unsigned short* __restrict__ bph,  // hi plane; lo plane at +448*Kp
    int Kp, const float* __restrict__ vec, int relu,
    unsigned short* __restrict__ ch, unsigned short* __restrict__ cl,
    const float* __restrict__ lw, float* __restrict__ lout)
{
    __shared__ unsigned short As[2][64*72];
    __shared__ unsigned short Bs[2][64*72];
    const unsigned short* bpl = bph + (size_t)448*Kp;
    int tid = threadIdx.x;
    int f = blockIdx.x;
    int xcd = f & 7, idx = f >> 3;          // 112 per XCD = 16 y-tiles x 7 x-tiles
    int yq = idx / 7;
    int ytile = xcd*16 + yq;
    int xtile = idx - yq*7;
    int bm = ytile*64, bn = xtile*64;
    int row = tid & 63, ks = tid >> 6;
    int w = tid >> 6, lane = tid & 63;
    int moff = (w & 1) * 32, noff = (w >> 1) * 32;
    int r31 = lane & 31, hh = lane >> 5;
    floatx16 acc;
    for (int i = 0; i < 16; ++i) acc[i] = 0.f;
    int nk16 = Kp >> 4;
    int nchunks = (Kp + 63) >> 6;
    int fragA = (moff + r31)*72 + hh*8;
    int fragB = (noff + r31)*72 + hh*8;
    int lbase = row*72 + ks*16;

    uint4 ah0, ah1, al0, al1, bh0, bh1, bl0, bl1;
    auto load_chunk = [&](int c) {
        int kg = (c << 2) + ks;
        int kb = kg << 4;
        ah0 = make_uint4(0,0,0,0); ah1 = ah0; al0 = ah0; al1 = ah0;
        bh0 = ah0; bh1 = ah0; bl0 = ah0; bl1 = ah0;
        if (kg < nk16) {
            const unsigned short *ph, *pl;
            if (kb < KA) {
                ph = a1h + (size_t)(bm+row)*sA + kb;
                pl = a1l + (size_t)(bm+row)*sA + kb;
            } else {
                ph = a2h + (size_t)(bm+row)*416 + (kb - KA);
                pl = a2l + (size_t)(bm+row)*416 + (kb - KA);
            }
            ah0 = *(const uint4*)ph;     ah1 = *(const uint4*)(ph+8);
            al0 = *(const uint4*)pl;     al1 = *(const uint4*)(pl+8);
            const unsigned short* qh = bph + (size_t)(bn+row)*Kp + kb;
            const unsigned short* ql = bpl + (size_t)(bn+row)*Kp + kb;
            bh0 = *(const uint4*)qh;     bh1 = *(const uint4*)(qh+8);
            bl0 = *(const uint4*)ql;     bl1 = *(const uint4*)(ql+8);
        }
    };
    load_chunk(0);
    for (int c = 0; c < nchunks; ++c) {
        __syncthreads();
        *(uint4*)&As[0][lbase]   = ah0;  *(uint4*)&As[0][lbase+8] = ah1;
        *(uint4*)&As[1][lbase]   = al0;  *(uint4*)&As[1][lbase+8] = al1;
        *(uint4*)&Bs[0][lbase]   = bh0;  *(uint4*)&Bs[0][lbase+8] = bh1;
        *(uint4*)&Bs[1][lbase]   = bl0;  *(uint4*)&Bs[1][lbase+8] = bl1;
        __syncthreads();
        if (c + 1 < nchunks) load_chunk(c + 1);   // overlaps with MFMA below
        #pragma unroll
        for (int s = 0; s < 4; ++s) {
            short8 fah = *(const short8*)&As[0][fragA + s*16];
            short8 fal = *(const short8*)&As[1][fragA + s*16];
            short8 fbh = *(const short8*)&Bs[0][fragB + s*16];
            short8 fbl = *(const short8*)&Bs[1][fragB + s*16];
            acc = __builtin_amdgcn_mfma_f32_32x32x16_bf16(fah, fbh, acc, 0, 0, 0);
            acc = __builtin_amdgcn_mfma_f32_32x32x16_bf16(fah, fbl, acc, 0, 0, 0);
            acc = __builtin_amdgcn_mfma_f32_32x32x16_bf16(fal, fbh, acc, 0, 0, 0);
        }
    }
    // epilogue: C/D layout col=lane&31, row=(reg&3)+8*(reg>>2)+4*(lane>>5)
    int gn = bn + noff + r31;
    bool ok = gn < 400;
    float vc = ok ? vec[gn] : 0.f;
    float vals[16];
    #pragma unroll
    for (int r = 0; r < 16; ++r) {
        int rr = (r & 3) + 8*(r >> 2) + 4*hh;
        int gm = bm + moff + rr;
        float v = acc[r] + vc;
        if (relu) v = fmaxf(v, 0.f);
        vals[r] = v;
        if (ok) {
            unsigned short h16, l16;
            split2(v, h16, l16);
            ch[(size_t)gm*400 + gn] = h16;
            cl[(size_t)gm*400 + gn] = l16;
        }
    }
    if (lw) {
        float wv = ok ? lw[gn] : 0.f;
        #pragma unroll
        for (int r = 0; r < 16; ++r) vals[r] *= wv;
        #pragma unroll
        for (int o = 1; o < 32; o <<= 1) {
            #pragma unroll
            for (int r = 0; r < 16; ++r) vals[r] += __shfl_xor(vals[r], o);
        }
        if (r31 == 0) {
            #pragma unroll
            for (int r = 0; r < 16; ++r) {
                int rr = (r & 3) + 8*(r >> 2) + 4*hh;
                atomicAdd(&lout[bm + moff + rr], vals[r]);
            }
        }
    }
}

// ---------------- host ----------------
static inline size_t align16(size_t x) { return (x + 15) & ~(size_t)15; }

extern "C" void kernel_launch(void* const* d_in, const int* in_sizes, int n_in,
                              void* d_out, int out_size, void* d_ws, size_t ws_size,
                              hipStream_t stream)
{
    const float* raw_dense  = (const float*)d_in[0];
    const int*   raw_sparse = (const int*)d_in[1];
    const float* emb   = (const float*)d_in[2];
    const float* Pd    = (const float*)d_in[3];
    const float* Ps    = (const float*)d_in[4];
    const float* Pb    = (const float*)d_in[5];
    const float* Wc    = (const float*)d_in[6];
    const float* bc    = (const float*)d_in[7];
    const float* clf_w = (const float*)d_in[8];
    const float* clf_b = (const float*)d_in[9];
    const float* a0 = (const float*)d_in[10];
    const float* a1 = (const float*)d_in[11];
    const float* a2 = (const float*)d_in[12];
    const float* a3 = (const float*)d_in[13];
    float* out = (float*)d_out;

    char* p = (char*)d_ws;
    auto alloc = [&](size_t bytes) { char* r = p; p += align16(bytes); return r; };

    float* scal    = (float*)alloc(32*4);
    float* partial = (float*)alloc(2*EMB_BLOCKS*4);
    float* csd     = (float*)alloc(400*4);
    float* css     = (float*)alloc(400*4);
    float* csb     = (float*)alloc(400*4);
    float* cv      = (float*)alloc(4*448*4);
    float* dv      = (float*)alloc(4*448*4);
    unsigned short* w0 = (unsigned short*)alloc((size_t)2*448*624*2);
    unsigned short* w1 = (unsigned short*)alloc((size_t)2*448*816*2);
    unsigned short* w2 = (unsigned short*)alloc((size_t)2*448*816*2);
    unsigned short* w3 = (unsigned short*)alloc((size_t)2*448*816*2);
    unsigned short* v0 = (unsigned short*)alloc((size_t)2*448*400*2);
    unsigned short* v1 = (unsigned short*)alloc((size_t)2*448*400*2);
    unsigned short* v2 = (unsigned short*)alloc((size_t)2*448*400*2);
    unsigned short* v3 = (unsigned short*)alloc((size_t)2*448*400*2);
    unsigned short* n0h = (unsigned short*)alloc((size_t)8192*208*2);
    unsigned short* n0l = (unsigned short*)alloc((size_t)8192*208*2);
    unsigned short* n1h = (unsigned short*)alloc((size_t)8192*416*2);
    unsigned short* n1l = (unsigned short*)alloc((size_t)8192*416*2);
    unsigned short* hh  = (unsigned short*)alloc((size_t)8192*400*2);
    unsigned short* hl  = (unsigned short*)alloc((size_t)8192*400*2);
    unsigned short* nAh = (unsigned short*)alloc((size_t)8192*400*2);
    unsigned short* nAl = (unsigned short*)alloc((size_t)8192*400*2);
    unsigned short* nBh = (unsigned short*)alloc((size_t)8192*400*2);
    unsigned short* nBl = (unsigned short*)alloc((size_t)8192*400*2);

    prep1_kernel<<<5,256,0,stream>>>(Pd,Ps,Pb,a0,a1,a2,a3,scal,csd,css,csb);
    embed_kernel<<<EMB_BLOCKS,256,0,stream>>>(raw_dense, raw_sparse, emb, n0h,n0l,n1h,n1l, partial);
    finalize_kernel<<<33,256,0,stream>>>(clf_b, partial, out);
    prep2_kernel<<<dim3(7,13,8),256,0,stream>>>(Pd,Ps,Pb,Wc,scal,w0,w1,w2,w3,v0,v1,v2,v3);
    prep3_kernel<<<4,256,0,stream>>>(scal,csd,css,csb,bc,cv,dv);

    // block 0: h = relu([node0|node1] @ w0 + cv0); node2 = h @ v0 + dv0 (+logits)
    mfma_gemm<<<896,256,0,stream>>>(n0h,n0l,208,208, n1h,n1l, w0, 624, cv+0,   1, hh,hl,  nullptr, nullptr);
    mfma_gemm<<<896,256,0,stream>>>(hh,hl,400,400, nullptr,nullptr, v0, 400, dv+0,   0, nAh,nAl, clf_w,      out);
    // block 1
    mfma_gemm<<<896,256,0,stream>>>(nAh,nAl,400,400, n1h,n1l, w1, 816, cv+448, 1, hh,hl,  nullptr, nullptr);
    mfma_gemm<<<896,256,0,stream>>>(hh,hl,400,400, nullptr,nullptr, v1, 400, dv+448, 0, nBh,nBl, clf_w+400,  out);
    // block 2
    mfma_gemm<<<896,256,0,stream>>>(nBh,nBl,400,400, n1h,n1l, w2, 816, cv+896, 1, hh,hl,  nullptr, nullptr);
    mfma_gemm<<<896,256,0,stream>>>(hh,hl,400,400, nullptr,nullptr, v2, 400, dv+896, 0, nAh,nAl, clf_w+800,  out);
    // block 3
    mfma_gemm<<<896,256,0,stream>>>(nAh,nAl,400,400, n1h,n1l, w3, 816, cv+1344, 1, hh,hl, nullptr, nullptr);
    mfma_gemm<<<896,256,0,stream>>>(hh,hl,400,400, nullptr,nullptr, v3, 400, dv+1344, 0, nBh,nBl, clf_w+1200, out);
}